// Round 1
// baseline (1158.623 us; speedup 1.0000x reference)
//
#include <hip/hip_runtime.h>
#include <hip/hip_bf16.h>
#include <math.h>

#define N_NODES 50000
#define N_EDGES 1600000
#define N_TOT   (N_EDGES + N_NODES)   // edges + self loops
#define N_GRAPHS 64

// ---------------------------------------------------------------------------
// Dense transforms: xl = x @ Wl, xr = x @ Wr
// One block per node, 128 threads: threads 0-63 -> Wl columns, 64-127 -> Wr.
// ---------------------------------------------------------------------------
__global__ __launch_bounds__(128) void gemm_128_64(
    const float* __restrict__ x, const float* __restrict__ Wl,
    const float* __restrict__ Wr, float* __restrict__ xl, float* __restrict__ xr) {
    __shared__ float xs[128];
    const int n = blockIdx.x;
    const int t = threadIdx.x;
    xs[t] = x[n * 128 + t];
    __syncthreads();
    const float* W = (t < 64) ? Wl : Wr;
    const int c = t & 63;
    float a = 0.f;
#pragma unroll
    for (int k = 0; k < 128; ++k) a = fmaf(xs[k], W[k * 64 + c], a);
    float* o = (t < 64) ? xl : xr;
    o[n * 64 + c] = a;
}

__global__ __launch_bounds__(128) void gemm_64_64(
    const float* __restrict__ h, const float* __restrict__ Wl,
    const float* __restrict__ Wr, float* __restrict__ xl, float* __restrict__ xr) {
    __shared__ float xs[64];
    const int n = blockIdx.x;
    const int t = threadIdx.x;
    if (t < 64) xs[t] = h[n * 64 + t];
    __syncthreads();
    const float* W = (t < 64) ? Wl : Wr;
    const int c = t & 63;
    float a = 0.f;
#pragma unroll
    for (int k = 0; k < 64; ++k) a = fmaf(xs[k], W[k * 64 + c], a);
    float* o = (t < 64) ? xl : xr;
    o[n * 64 + c] = a;
}

// ---------------------------------------------------------------------------
// Edge pass, layer 1 (2 heads x 32 ch). One wave per edge.
// lane = h*32 + c. score_h = sum_c att[h,c]*leakyrelu(xl[src]+xr[dst]).
// No max-subtraction (cancels in e/sum(e); scores are O(10), no overflow).
// acc[dst,lane] += exp(score_h)*xl[src,lane];  s[dst,h] += exp(score_h)
// ---------------------------------------------------------------------------
__global__ __launch_bounds__(256) void edge_l1(
    const int* __restrict__ ei, const float* __restrict__ xl,
    const float* __restrict__ xr, const float* __restrict__ att,
    float* __restrict__ acc, float* __restrict__ s) {
    const int e = (int)(((long long)blockIdx.x * 256 + threadIdx.x) >> 6);
    const int lane = threadIdx.x & 63;
    if (e >= N_TOT) return;
    int src, dst;
    if (e < N_EDGES) { src = ei[e]; dst = ei[N_EDGES + e]; }
    else             { src = e - N_EDGES; dst = src; }
    const float xlv = xl[src * 64 + lane];
    const float xrv = xr[dst * 64 + lane];
    float u = xlv + xrv;
    u = u > 0.f ? u : 0.2f * u;
    float v = att[lane] * u;
    // butterfly within each 32-lane half (per head)
    v += __shfl_xor(v, 1);
    v += __shfl_xor(v, 2);
    v += __shfl_xor(v, 4);
    v += __shfl_xor(v, 8);
    v += __shfl_xor(v, 16);
    const float ev = expf(v);
    unsafeAtomicAdd(&acc[dst * 64 + lane], ev * xlv);
    if ((lane & 31) == 0) unsafeAtomicAdd(&s[dst * 2 + (lane >> 5)], ev);
}

// Edge pass, layer 2 (1 head x 64 ch): full 64-lane reduction.
__global__ __launch_bounds__(256) void edge_l2(
    const int* __restrict__ ei, const float* __restrict__ xl,
    const float* __restrict__ xr, const float* __restrict__ att,
    float* __restrict__ acc, float* __restrict__ s) {
    const int e = (int)(((long long)blockIdx.x * 256 + threadIdx.x) >> 6);
    const int lane = threadIdx.x & 63;
    if (e >= N_TOT) return;
    int src, dst;
    if (e < N_EDGES) { src = ei[e]; dst = ei[N_EDGES + e]; }
    else             { src = e - N_EDGES; dst = src; }
    const float xlv = xl[src * 64 + lane];
    const float xrv = xr[dst * 64 + lane];
    float u = xlv + xrv;
    u = u > 0.f ? u : 0.2f * u;
    float v = att[lane] * u;
    v += __shfl_xor(v, 1);
    v += __shfl_xor(v, 2);
    v += __shfl_xor(v, 4);
    v += __shfl_xor(v, 8);
    v += __shfl_xor(v, 16);
    v += __shfl_xor(v, 32);
    const float ev = expf(v);
    unsafeAtomicAdd(&acc[dst * 64 + lane], ev * xlv);
    if (lane == 0) unsafeAtomicAdd(&s[dst], ev);
}

// h1[n,t] = elu(acc[n,t]/(s[n,head(t)]+1e-16) + b1[t])
__global__ __launch_bounds__(256) void finalize1(
    const float* __restrict__ acc, const float* __restrict__ s,
    const float* __restrict__ b1, float* __restrict__ h1) {
    const int i = blockIdx.x * 256 + threadIdx.x;
    if (i >= N_NODES * 64) return;
    const int n = i >> 6, t = i & 63;
    const float denom = s[n * 2 + (t >> 5)] + 1e-16f;
    float v = acc[i] / denom + b1[t];
    h1[i] = v > 0.f ? v : expm1f(v);
}

// Finalize layer 2 + mean-pool accumulation. batch is sorted; each 64-thread
// block walks 64 consecutive nodes keeping a running per-graph partial that is
// flushed atomically when the graph id changes (~2 flushes/block).
__global__ __launch_bounds__(64) void pool_kernel(
    const float* __restrict__ acc, const float* __restrict__ s,
    const float* __restrict__ b2, const int* __restrict__ batch,
    float* __restrict__ pooled, float* __restrict__ cnt) {
    const int t = threadIdx.x;
    const int base = blockIdx.x * 64;
    float local = 0.f, lc = 0.f;
    int cur = -1;
    for (int j = 0; j < 64; ++j) {
        const int n = base + j;
        if (n >= N_NODES) break;
        const int g = batch[n];
        if (g != cur) {
            if (cur >= 0) {
                unsafeAtomicAdd(&pooled[cur * 64 + t], local);
                if (t == 0) unsafeAtomicAdd(&cnt[cur], lc);
            }
            cur = g; local = 0.f; lc = 0.f;
        }
        const float denom = s[n] + 1e-16f;
        float v = acc[n * 64 + t] / denom + b2[t];
        v = v > 0.f ? v : expm1f(v);
        local += v; lc += 1.f;
    }
    if (cur >= 0) {
        unsafeAtomicAdd(&pooled[cur * 64 + t], local);
        if (t == 0) unsafeAtomicAdd(&cnt[cur], lc);
    }
}

// out[g,k] = (pooled[g,:]/max(cnt,1)) @ lin_w[:,k] + lin_b[k]
__global__ __launch_bounds__(128) void head_kernel(
    const float* __restrict__ pooled, const float* __restrict__ cnt,
    const float* __restrict__ lin_w, const float* __restrict__ lin_b,
    float* __restrict__ out) {
    const int i = threadIdx.x;          // 0..127 -> (g, k)
    const int g = i >> 1, k = i & 1;
    float c = cnt[g];
    c = c > 1.f ? c : 1.f;
    float a = 0.f;
#pragma unroll
    for (int j = 0; j < 64; ++j) a = fmaf(pooled[g * 64 + j] / c, lin_w[j * 2 + k], a);
    out[i] = a + lin_b[k];
}

extern "C" void kernel_launch(void* const* d_in, const int* in_sizes, int n_in,
                              void* d_out, int out_size, void* d_ws, size_t ws_size,
                              hipStream_t stream) {
    const float* x     = (const float*)d_in[0];
    const int*   ei    = (const int*)d_in[1];
    const int*   batch = (const int*)d_in[2];
    const float* Wl1   = (const float*)d_in[3];
    const float* Wr1   = (const float*)d_in[4];
    const float* att1  = (const float*)d_in[5];
    const float* b1    = (const float*)d_in[6];
    const float* Wl2   = (const float*)d_in[7];
    const float* Wr2   = (const float*)d_in[8];
    const float* att2  = (const float*)d_in[9];
    const float* b2    = (const float*)d_in[10];
    const float* lin_w = (const float*)d_in[11];
    const float* lin_b = (const float*)d_in[12];

    float* ws = (float*)d_ws;
    float* xl     = ws;                    // 50000*64
    float* xr     = ws + 3200000;          // 50000*64
    float* h1     = ws + 6400000;          // 50000*64
    float* acc    = ws + 9600000;          // 50000*64   (reused both layers)
    float* s      = ws + 12800000;         // 50000*2    (reused both layers)
    float* pooled = ws + 12900000;         // 64*64
    float* cnt    = ws + 12904096;         // 64
    // total 12,904,160 floats ≈ 51.6 MB

    // zero acc, s, pooled, cnt (ws is poisoned 0xAA before each call)
    hipMemsetAsync(acc, 0, (size_t)(3200000 + 100000 + 4096 + 64) * sizeof(float), stream);

    const int eblocks = (N_TOT + 3) / 4;   // 4 waves (edges) per 256-thread block

    // ---- layer 1 ----
    gemm_128_64<<<N_NODES, 128, 0, stream>>>(x, Wl1, Wr1, xl, xr);
    edge_l1<<<eblocks, 256, 0, stream>>>(ei, xl, xr, att1, acc, s);
    finalize1<<<(N_NODES * 64) / 256, 256, 0, stream>>>(acc, s, b1, h1);

    // ---- layer 2 ----
    hipMemsetAsync(acc, 0, (size_t)(3200000 + 100000) * sizeof(float), stream);
    gemm_64_64<<<N_NODES, 128, 0, stream>>>(h1, Wl2, Wr2, xl, xr);
    edge_l2<<<eblocks, 256, 0, stream>>>(ei, xl, xr, att2, acc, s);

    // ---- pool + head ----
    pool_kernel<<<(N_NODES + 63) / 64, 64, 0, stream>>>(acc, s, b2, batch, pooled, cnt);
    head_kernel<<<1, 128, 0, stream>>>(pooled, cnt, lin_w, lin_b, (float*)d_out);
}

// Round 2
// 699.191 us; speedup vs baseline: 1.6571x; 1.6571x over previous
//
#include <hip/hip_runtime.h>
#include <hip/hip_bf16.h>
#include <math.h>

#define N_NODES 50000
#define N_EDGES 1600000
#define N_GRAPHS 64
#define SCAN_BLK 512
#define N_SCAN_BLOCKS ((N_NODES + SCAN_BLK - 1) / SCAN_BLK)   // 98

// ---------------------------------------------------------------------------
// Dense transforms: xl = x @ Wl, xr = x @ Wr
// ---------------------------------------------------------------------------
__global__ __launch_bounds__(128) void gemm_128_64(
    const float* __restrict__ x, const float* __restrict__ Wl,
    const float* __restrict__ Wr, float* __restrict__ xl, float* __restrict__ xr) {
    __shared__ float xs[128];
    const int n = blockIdx.x;
    const int t = threadIdx.x;
    xs[t] = x[n * 128 + t];
    __syncthreads();
    const float* W = (t < 64) ? Wl : Wr;
    const int c = t & 63;
    float a = 0.f;
#pragma unroll
    for (int k = 0; k < 128; ++k) a = fmaf(xs[k], W[k * 64 + c], a);
    float* o = (t < 64) ? xl : xr;
    o[n * 64 + c] = a;
}

__global__ __launch_bounds__(128) void gemm_64_64(
    const float* __restrict__ h, const float* __restrict__ Wl,
    const float* __restrict__ Wr, float* __restrict__ xl, float* __restrict__ xr) {
    __shared__ float xs[64];
    const int n = blockIdx.x;
    const int t = threadIdx.x;
    if (t < 64) xs[t] = h[n * 64 + t];
    __syncthreads();
    const float* W = (t < 64) ? Wl : Wr;
    const int c = t & 63;
    float a = 0.f;
#pragma unroll
    for (int k = 0; k < 64; ++k) a = fmaf(xs[k], W[k * 64 + c], a);
    float* o = (t < 64) ? xl : xr;
    o[n * 64 + c] = a;
}

// ---------------------------------------------------------------------------
// CSR build: histogram by dst -> exclusive scan -> scatter src into dst order.
// Self-loops are NOT stored; node kernels add them implicitly.
// ---------------------------------------------------------------------------
__global__ __launch_bounds__(256) void hist_kernel(
    const int* __restrict__ ei, int* __restrict__ deg) {
    const int e = blockIdx.x * 256 + threadIdx.x;
    if (e < N_EDGES) atomicAdd(&deg[ei[N_EDGES + e]], 1);
}

__global__ __launch_bounds__(SCAN_BLK) void scan1_kernel(
    const int* __restrict__ deg, int* __restrict__ rowstart,
    int* __restrict__ blockSums) {
    __shared__ int tmp[SCAN_BLK];
    const int t = threadIdx.x;
    const int idx = blockIdx.x * SCAN_BLK + t;
    const int v0 = (idx < N_NODES) ? deg[idx] : 0;
    tmp[t] = v0;
    __syncthreads();
    for (int off = 1; off < SCAN_BLK; off <<= 1) {
        int v = (t >= off) ? tmp[t - off] : 0;
        __syncthreads();
        tmp[t] += v;
        __syncthreads();
    }
    if (idx < N_NODES) rowstart[idx] = tmp[t] - v0;  // exclusive
    if (t == SCAN_BLK - 1) blockSums[blockIdx.x] = tmp[t];
}

__global__ __launch_bounds__(128) void scan2_kernel(
    const int* __restrict__ blockSums, int* __restrict__ blockOff) {
    __shared__ int tmp[128];
    const int t = threadIdx.x;
    const int v0 = (t < N_SCAN_BLOCKS) ? blockSums[t] : 0;
    tmp[t] = v0;
    __syncthreads();
    for (int off = 1; off < 128; off <<= 1) {
        int v = (t >= off) ? tmp[t - off] : 0;
        __syncthreads();
        tmp[t] += v;
        __syncthreads();
    }
    if (t < N_SCAN_BLOCKS) blockOff[t] = tmp[t] - v0;  // exclusive
}

__global__ __launch_bounds__(256) void scan3_kernel(
    int* __restrict__ rowstart, const int* __restrict__ blockOff) {
    const int idx = blockIdx.x * 256 + threadIdx.x;
    if (idx < N_NODES) rowstart[idx] += blockOff[idx / SCAN_BLK];
    else if (idx == N_NODES) rowstart[N_NODES] = N_EDGES;
}

__global__ __launch_bounds__(256) void scatter_kernel(
    const int* __restrict__ ei, const int* __restrict__ rowstart,
    int* __restrict__ cursor, int* __restrict__ sorted_src) {
    const int e = blockIdx.x * 256 + threadIdx.x;
    if (e >= N_EDGES) return;
    const int d = ei[N_EDGES + e];
    const int pos = atomicAdd(&cursor[d], 1);
    sorted_src[rowstart[d] + pos] = ei[e];
}

// ---------------------------------------------------------------------------
// Node-centric GATv2 layer: one wave per dst node, edges gathered from CSR,
// accumulated in registers, single write. Softmax denominator is a per-lane
// register (all lanes of a head hold the same exp(score) after the butterfly).
// Fuses divide + bias + ELU. No max-subtraction (cancels; scores are O(10)).
// ---------------------------------------------------------------------------
__global__ __launch_bounds__(256) void node_l1(
    const int* __restrict__ rowstart, const int* __restrict__ sorted_src,
    const float* __restrict__ xl, const float* __restrict__ xr,
    const float* __restrict__ att, const float* __restrict__ b1,
    float* __restrict__ h1) {
    const int n = (blockIdx.x * 256 + threadIdx.x) >> 6;
    const int lane = threadIdx.x & 63;
    const float xrn = xr[n * 64 + lane];
    const float xln = xl[n * 64 + lane];
    const float attv = att[lane];
    // self loop
    float u = xln + xrn;
    u = u > 0.f ? u : 0.2f * u;
    float v = attv * u;
    v += __shfl_xor(v, 1);
    v += __shfl_xor(v, 2);
    v += __shfl_xor(v, 4);
    v += __shfl_xor(v, 8);
    v += __shfl_xor(v, 16);
    float ev = __expf(v);
    float accv = ev * xln;
    float ssum = ev;
    const int beg = __builtin_amdgcn_readfirstlane(rowstart[n]);
    const int end = __builtin_amdgcn_readfirstlane(rowstart[n + 1]);
    for (int i = beg; i < end; ++i) {
        const int src = sorted_src[i];
        const float xlv = xl[src * 64 + lane];
        float u2 = xlv + xrn;
        u2 = u2 > 0.f ? u2 : 0.2f * u2;
        float v2 = attv * u2;
        v2 += __shfl_xor(v2, 1);
        v2 += __shfl_xor(v2, 2);
        v2 += __shfl_xor(v2, 4);
        v2 += __shfl_xor(v2, 8);
        v2 += __shfl_xor(v2, 16);
        const float e2 = __expf(v2);
        accv = fmaf(e2, xlv, accv);
        ssum += e2;
    }
    float o = accv / (ssum + 1e-16f) + b1[lane];
    h1[n * 64 + lane] = o > 0.f ? o : expm1f(o);
}

__global__ __launch_bounds__(256) void node_l2(
    const int* __restrict__ rowstart, const int* __restrict__ sorted_src,
    const float* __restrict__ xl, const float* __restrict__ xr,
    const float* __restrict__ att, const float* __restrict__ b2,
    float* __restrict__ h2) {
    const int n = (blockIdx.x * 256 + threadIdx.x) >> 6;
    const int lane = threadIdx.x & 63;
    const float xrn = xr[n * 64 + lane];
    const float xln = xl[n * 64 + lane];
    const float attv = att[lane];
    float u = xln + xrn;
    u = u > 0.f ? u : 0.2f * u;
    float v = attv * u;
    v += __shfl_xor(v, 1);
    v += __shfl_xor(v, 2);
    v += __shfl_xor(v, 4);
    v += __shfl_xor(v, 8);
    v += __shfl_xor(v, 16);
    v += __shfl_xor(v, 32);
    float ev = __expf(v);
    float accv = ev * xln;
    float ssum = ev;
    const int beg = __builtin_amdgcn_readfirstlane(rowstart[n]);
    const int end = __builtin_amdgcn_readfirstlane(rowstart[n + 1]);
    for (int i = beg; i < end; ++i) {
        const int src = sorted_src[i];
        const float xlv = xl[src * 64 + lane];
        float u2 = xlv + xrn;
        u2 = u2 > 0.f ? u2 : 0.2f * u2;
        float v2 = attv * u2;
        v2 += __shfl_xor(v2, 1);
        v2 += __shfl_xor(v2, 2);
        v2 += __shfl_xor(v2, 4);
        v2 += __shfl_xor(v2, 8);
        v2 += __shfl_xor(v2, 16);
        v2 += __shfl_xor(v2, 32);
        const float e2 = __expf(v2);
        accv = fmaf(e2, xlv, accv);
        ssum += e2;
    }
    float o = accv / (ssum + 1e-16f) + b2[lane];
    h2[n * 64 + lane] = o > 0.f ? o : expm1f(o);
}

// Mean-pool accumulation over sorted batch ids; h2 is already final layer-2
// output (bias+ELU applied).
__global__ __launch_bounds__(64) void pool_kernel(
    const float* __restrict__ h2, const int* __restrict__ batch,
    float* __restrict__ pooled, float* __restrict__ cnt) {
    const int t = threadIdx.x;
    const int base = blockIdx.x * 64;
    float local = 0.f, lc = 0.f;
    int cur = -1;
    for (int j = 0; j < 64; ++j) {
        const int n = base + j;
        if (n >= N_NODES) break;
        const int g = batch[n];
        if (g != cur) {
            if (cur >= 0) {
                unsafeAtomicAdd(&pooled[cur * 64 + t], local);
                if (t == 0) unsafeAtomicAdd(&cnt[cur], lc);
            }
            cur = g; local = 0.f; lc = 0.f;
        }
        local += h2[n * 64 + t];
        lc += 1.f;
    }
    if (cur >= 0) {
        unsafeAtomicAdd(&pooled[cur * 64 + t], local);
        if (t == 0) unsafeAtomicAdd(&cnt[cur], lc);
    }
}

__global__ __launch_bounds__(128) void head_kernel(
    const float* __restrict__ pooled, const float* __restrict__ cnt,
    const float* __restrict__ lin_w, const float* __restrict__ lin_b,
    float* __restrict__ out) {
    const int i = threadIdx.x;          // 0..127 -> (g, k)
    const int g = i >> 1, k = i & 1;
    float c = cnt[g];
    c = c > 1.f ? c : 1.f;
    float a = 0.f;
#pragma unroll
    for (int j = 0; j < 64; ++j) a = fmaf(pooled[g * 64 + j] / c, lin_w[j * 2 + k], a);
    out[i] = a + lin_b[k];
}

extern "C" void kernel_launch(void* const* d_in, const int* in_sizes, int n_in,
                              void* d_out, int out_size, void* d_ws, size_t ws_size,
                              hipStream_t stream) {
    const float* x     = (const float*)d_in[0];
    const int*   ei    = (const int*)d_in[1];
    const int*   batch = (const int*)d_in[2];
    const float* Wl1   = (const float*)d_in[3];
    const float* Wr1   = (const float*)d_in[4];
    const float* att1  = (const float*)d_in[5];
    const float* b1    = (const float*)d_in[6];
    const float* Wl2   = (const float*)d_in[7];
    const float* Wr2   = (const float*)d_in[8];
    const float* att2  = (const float*)d_in[9];
    const float* b2    = (const float*)d_in[10];
    const float* lin_w = (const float*)d_in[11];
    const float* lin_b = (const float*)d_in[12];

    float* ws = (float*)d_ws;
    float* xl        = ws;                          // 3,200,000
    float* xr        = ws + 3200000;                // 3,200,000
    float* h1        = ws + 6400000;                // 3,200,000 (reused as h2)
    int*   sorted    = (int*)(ws + 9600000);        // 1,600,000
    int*   rowstart  = (int*)(ws + 11200000);       // 50,001
    int*   deg       = (int*)(ws + 11251000);       // 50,000  -- start of zero region
    int*   cursor    = (int*)(ws + 11301000);       // 50,000
    float* pooled    = ws + 11351000;               // 4,096
    float* cnt       = ws + 11355096;               // 64
    int*   blockSums = (int*)(ws + 11356000);       // 128
    int*   blockOff  = (int*)(ws + 11356128);       // 128
    // total ~11.36M floats ~= 45.4 MB

    // zero deg, cursor, pooled, cnt (contiguous)
    hipMemsetAsync(deg, 0, (size_t)(50000 + 50000 + 4096 + 64) * sizeof(float), stream);

    // ---- CSR build (dst-sorted edges) ----
    hist_kernel<<<(N_EDGES + 255) / 256, 256, 0, stream>>>(ei, deg);
    scan1_kernel<<<N_SCAN_BLOCKS, SCAN_BLK, 0, stream>>>(deg, rowstart, blockSums);
    scan2_kernel<<<1, 128, 0, stream>>>(blockSums, blockOff);
    scan3_kernel<<<(N_SCAN_BLOCKS * SCAN_BLK + 256) / 256, 256, 0, stream>>>(rowstart, blockOff);
    scatter_kernel<<<(N_EDGES + 255) / 256, 256, 0, stream>>>(ei, rowstart, cursor, sorted);

    // ---- layer 1 ----
    gemm_128_64<<<N_NODES, 128, 0, stream>>>(x, Wl1, Wr1, xl, xr);
    node_l1<<<N_NODES / 4, 256, 0, stream>>>(rowstart, sorted, xl, xr, att1, b1, h1);

    // ---- layer 2 (h2 reuses h1 buffer; gemm consumed h1 first) ----
    gemm_64_64<<<N_NODES, 128, 0, stream>>>(h1, Wl2, Wr2, xl, xr);
    node_l2<<<N_NODES / 4, 256, 0, stream>>>(rowstart, sorted, xl, xr, att2, b2, h1);

    // ---- pool + head ----
    pool_kernel<<<(N_NODES + 63) / 64, 64, 0, stream>>>(h1, batch, pooled, cnt);
    head_kernel<<<1, 128, 0, stream>>>(pooled, cnt, lin_w, lin_b, (float*)d_out);
}

// Round 3
// 534.461 us; speedup vs baseline: 2.1678x; 1.3082x over previous
//
#include <hip/hip_runtime.h>
#include <hip/hip_bf16.h>
#include <math.h>

#define N_NODES 50000
#define N_EDGES 1600000
#define N_GRAPHS 64
#define SCAN_BLK 512
#define N_SCAN_BLOCKS ((N_NODES + SCAN_BLK - 1) / SCAN_BLK)   // 98

// ---------------------------------------------------------------------------
// DPP cross-lane add helpers (VALU pipe, no LDS). Row = 16 lanes on gfx9xx.
// quad_perm[1,0,3,2]=0xB1 (xor1), quad_perm[2,3,0,1]=0x4E (xor2),
// row_half_mirror=0x141 (other quad in 8-group), row_mirror=0x140 (other 8).
// After the 4 steps every lane of a 16-row holds the row sum.
// ---------------------------------------------------------------------------
template <int CTRL>
__device__ __forceinline__ float dpp_add(float v) {
    int r = __builtin_amdgcn_update_dpp(0, __builtin_bit_cast(int, v), CTRL, 0xF, 0xF, true);
    return v + __builtin_bit_cast(float, r);
}

__device__ __forceinline__ float red16(float v) {
    v = dpp_add<0xB1>(v);
    v = dpp_add<0x4E>(v);
    v = dpp_add<0x141>(v);
    v = dpp_add<0x140>(v);
    return v;
}

// exp(score) for layer 1 (2 heads x 32 lanes): reduce within 32-lane head.
__device__ __forceinline__ float edge_ev_l1(float xlv, float xrn, float attv) {
    float u = xlv + xrn;
    u = u > 0.f ? u : 0.2f * u;
    float v = red16(attv * u);
    v += __shfl_xor(v, 16);
    return __expf(v);
}

// exp(score) for layer 2 (1 head x 64 lanes): reduce across full wave.
__device__ __forceinline__ float edge_ev_l2(float xlv, float xrn, float attv) {
    float u = xlv + xrn;
    u = u > 0.f ? u : 0.2f * u;
    float v = red16(attv * u);
    v += __shfl_xor(v, 16);
    v += __shfl_xor(v, 32);
    return __expf(v);
}

// ---------------------------------------------------------------------------
// Dense transforms: xl = x @ Wl, xr = x @ Wr
// ---------------------------------------------------------------------------
__global__ __launch_bounds__(128) void gemm_128_64(
    const float* __restrict__ x, const float* __restrict__ Wl,
    const float* __restrict__ Wr, float* __restrict__ xl, float* __restrict__ xr) {
    __shared__ float xs[128];
    const int n = blockIdx.x;
    const int t = threadIdx.x;
    xs[t] = x[n * 128 + t];
    __syncthreads();
    const float* W = (t < 64) ? Wl : Wr;
    const int c = t & 63;
    float a = 0.f;
#pragma unroll
    for (int k = 0; k < 128; ++k) a = fmaf(xs[k], W[k * 64 + c], a);
    float* o = (t < 64) ? xl : xr;
    o[n * 64 + c] = a;
}

__global__ __launch_bounds__(128) void gemm_64_64(
    const float* __restrict__ h, const float* __restrict__ Wl,
    const float* __restrict__ Wr, float* __restrict__ xl, float* __restrict__ xr) {
    __shared__ float xs[64];
    const int n = blockIdx.x;
    const int t = threadIdx.x;
    if (t < 64) xs[t] = h[n * 64 + t];
    __syncthreads();
    const float* W = (t < 64) ? Wl : Wr;
    const int c = t & 63;
    float a = 0.f;
#pragma unroll
    for (int k = 0; k < 64; ++k) a = fmaf(xs[k], W[k * 64 + c], a);
    float* o = (t < 64) ? xl : xr;
    o[n * 64 + c] = a;
}

// ---------------------------------------------------------------------------
// CSR build: histogram by dst -> exclusive scan -> scatter src into dst order.
// Self-loops are NOT stored; node kernels add them implicitly.
// ---------------------------------------------------------------------------
__global__ __launch_bounds__(256) void hist_kernel(
    const int* __restrict__ ei, int* __restrict__ deg) {
    const int e = blockIdx.x * 256 + threadIdx.x;
    if (e < N_EDGES) atomicAdd(&deg[ei[N_EDGES + e]], 1);
}

__global__ __launch_bounds__(SCAN_BLK) void scan1_kernel(
    const int* __restrict__ deg, int* __restrict__ rowstart,
    int* __restrict__ blockSums) {
    __shared__ int tmp[SCAN_BLK];
    const int t = threadIdx.x;
    const int idx = blockIdx.x * SCAN_BLK + t;
    const int v0 = (idx < N_NODES) ? deg[idx] : 0;
    tmp[t] = v0;
    __syncthreads();
    for (int off = 1; off < SCAN_BLK; off <<= 1) {
        int v = (t >= off) ? tmp[t - off] : 0;
        __syncthreads();
        tmp[t] += v;
        __syncthreads();
    }
    if (idx < N_NODES) rowstart[idx] = tmp[t] - v0;  // exclusive
    if (t == SCAN_BLK - 1) blockSums[blockIdx.x] = tmp[t];
}

__global__ __launch_bounds__(128) void scan2_kernel(
    const int* __restrict__ blockSums, int* __restrict__ blockOff) {
    __shared__ int tmp[128];
    const int t = threadIdx.x;
    const int v0 = (t < N_SCAN_BLOCKS) ? blockSums[t] : 0;
    tmp[t] = v0;
    __syncthreads();
    for (int off = 1; off < 128; off <<= 1) {
        int v = (t >= off) ? tmp[t - off] : 0;
        __syncthreads();
        tmp[t] += v;
        __syncthreads();
    }
    if (t < N_SCAN_BLOCKS) blockOff[t] = tmp[t] - v0;  // exclusive
}

__global__ __launch_bounds__(256) void scan3_kernel(
    int* __restrict__ rowstart, const int* __restrict__ blockOff) {
    const int idx = blockIdx.x * 256 + threadIdx.x;
    if (idx < N_NODES) rowstart[idx] += blockOff[idx / SCAN_BLK];
    else if (idx == N_NODES) rowstart[N_NODES] = N_EDGES;
}

__global__ __launch_bounds__(256) void scatter_kernel(
    const int* __restrict__ ei, const int* __restrict__ rowstart,
    int* __restrict__ cursor, int* __restrict__ sorted_src) {
    const int e = blockIdx.x * 256 + threadIdx.x;
    if (e >= N_EDGES) return;
    const int d = ei[N_EDGES + e];
    const int pos = atomicAdd(&cursor[d], 1);
    sorted_src[rowstart[d] + pos] = ei[e];
}

// ---------------------------------------------------------------------------
// Node-centric GATv2 layer: one wave per dst node. Edge loop unrolled x4 with
// independent gather+reduce chains for ILP. DPP reduction on the VALU pipe.
// ---------------------------------------------------------------------------
__global__ __launch_bounds__(256) void node_l1(
    const int* __restrict__ rowstart, const int* __restrict__ sorted_src,
    const float* __restrict__ xl, const float* __restrict__ xr,
    const float* __restrict__ att, const float* __restrict__ b1,
    float* __restrict__ h1) {
    const int n = (blockIdx.x * 256 + threadIdx.x) >> 6;
    const int lane = threadIdx.x & 63;
    const float xrn = xr[n * 64 + lane];
    const float xln = xl[n * 64 + lane];
    const float attv = att[lane];
    // self loop
    float ev = edge_ev_l1(xln, xrn, attv);
    float accv = ev * xln;
    float ssum = ev;
    const int beg = __builtin_amdgcn_readfirstlane(rowstart[n]);
    const int end = __builtin_amdgcn_readfirstlane(rowstart[n + 1]);
    int i = beg;
    for (; i + 3 < end; i += 4) {
        const int s0 = sorted_src[i + 0];
        const int s1 = sorted_src[i + 1];
        const int s2 = sorted_src[i + 2];
        const int s3 = sorted_src[i + 3];
        const float a0 = xl[s0 * 64 + lane];
        const float a1 = xl[s1 * 64 + lane];
        const float a2 = xl[s2 * 64 + lane];
        const float a3 = xl[s3 * 64 + lane];
        const float e0 = edge_ev_l1(a0, xrn, attv);
        const float e1 = edge_ev_l1(a1, xrn, attv);
        const float e2 = edge_ev_l1(a2, xrn, attv);
        const float e3 = edge_ev_l1(a3, xrn, attv);
        accv = fmaf(e0, a0, accv);
        accv = fmaf(e1, a1, accv);
        accv = fmaf(e2, a2, accv);
        accv = fmaf(e3, a3, accv);
        ssum += (e0 + e1) + (e2 + e3);
    }
    for (; i < end; ++i) {
        const int src = sorted_src[i];
        const float xlv = xl[src * 64 + lane];
        const float e2 = edge_ev_l1(xlv, xrn, attv);
        accv = fmaf(e2, xlv, accv);
        ssum += e2;
    }
    float o = accv / (ssum + 1e-16f) + b1[lane];
    h1[n * 64 + lane] = o > 0.f ? o : expm1f(o);
}

__global__ __launch_bounds__(256) void node_l2(
    const int* __restrict__ rowstart, const int* __restrict__ sorted_src,
    const float* __restrict__ xl, const float* __restrict__ xr,
    const float* __restrict__ att, const float* __restrict__ b2,
    float* __restrict__ h2) {
    const int n = (blockIdx.x * 256 + threadIdx.x) >> 6;
    const int lane = threadIdx.x & 63;
    const float xrn = xr[n * 64 + lane];
    const float xln = xl[n * 64 + lane];
    const float attv = att[lane];
    float ev = edge_ev_l2(xln, xrn, attv);
    float accv = ev * xln;
    float ssum = ev;
    const int beg = __builtin_amdgcn_readfirstlane(rowstart[n]);
    const int end = __builtin_amdgcn_readfirstlane(rowstart[n + 1]);
    int i = beg;
    for (; i + 3 < end; i += 4) {
        const int s0 = sorted_src[i + 0];
        const int s1 = sorted_src[i + 1];
        const int s2 = sorted_src[i + 2];
        const int s3 = sorted_src[i + 3];
        const float a0 = xl[s0 * 64 + lane];
        const float a1 = xl[s1 * 64 + lane];
        const float a2 = xl[s2 * 64 + lane];
        const float a3 = xl[s3 * 64 + lane];
        const float e0 = edge_ev_l2(a0, xrn, attv);
        const float e1 = edge_ev_l2(a1, xrn, attv);
        const float e2 = edge_ev_l2(a2, xrn, attv);
        const float e3 = edge_ev_l2(a3, xrn, attv);
        accv = fmaf(e0, a0, accv);
        accv = fmaf(e1, a1, accv);
        accv = fmaf(e2, a2, accv);
        accv = fmaf(e3, a3, accv);
        ssum += (e0 + e1) + (e2 + e3);
    }
    for (; i < end; ++i) {
        const int src = sorted_src[i];
        const float xlv = xl[src * 64 + lane];
        const float e2 = edge_ev_l2(xlv, xrn, attv);
        accv = fmaf(e2, xlv, accv);
        ssum += e2;
    }
    float o = accv / (ssum + 1e-16f) + b2[lane];
    h2[n * 64 + lane] = o > 0.f ? o : expm1f(o);
}

// Mean-pool accumulation over sorted batch ids.
__global__ __launch_bounds__(64) void pool_kernel(
    const float* __restrict__ h2, const int* __restrict__ batch,
    float* __restrict__ pooled, float* __restrict__ cnt) {
    const int t = threadIdx.x;
    const int base = blockIdx.x * 64;
    float local = 0.f, lc = 0.f;
    int cur = -1;
    for (int j = 0; j < 64; ++j) {
        const int n = base + j;
        if (n >= N_NODES) break;
        const int g = batch[n];
        if (g != cur) {
            if (cur >= 0) {
                unsafeAtomicAdd(&pooled[cur * 64 + t], local);
                if (t == 0) unsafeAtomicAdd(&cnt[cur], lc);
            }
            cur = g; local = 0.f; lc = 0.f;
        }
        local += h2[n * 64 + t];
        lc += 1.f;
    }
    if (cur >= 0) {
        unsafeAtomicAdd(&pooled[cur * 64 + t], local);
        if (t == 0) unsafeAtomicAdd(&cnt[cur], lc);
    }
}

__global__ __launch_bounds__(128) void head_kernel(
    const float* __restrict__ pooled, const float* __restrict__ cnt,
    const float* __restrict__ lin_w, const float* __restrict__ lin_b,
    float* __restrict__ out) {
    const int i = threadIdx.x;          // 0..127 -> (g, k)
    const int g = i >> 1, k = i & 1;
    float c = cnt[g];
    c = c > 1.f ? c : 1.f;
    float a = 0.f;
#pragma unroll
    for (int j = 0; j < 64; ++j) a = fmaf(pooled[g * 64 + j] / c, lin_w[j * 2 + k], a);
    out[i] = a + lin_b[k];
}

extern "C" void kernel_launch(void* const* d_in, const int* in_sizes, int n_in,
                              void* d_out, int out_size, void* d_ws, size_t ws_size,
                              hipStream_t stream) {
    const float* x     = (const float*)d_in[0];
    const int*   ei    = (const int*)d_in[1];
    const int*   batch = (const int*)d_in[2];
    const float* Wl1   = (const float*)d_in[3];
    const float* Wr1   = (const float*)d_in[4];
    const float* att1  = (const float*)d_in[5];
    const float* b1    = (const float*)d_in[6];
    const float* Wl2   = (const float*)d_in[7];
    const float* Wr2   = (const float*)d_in[8];
    const float* att2  = (const float*)d_in[9];
    const float* b2    = (const float*)d_in[10];
    const float* lin_w = (const float*)d_in[11];
    const float* lin_b = (const float*)d_in[12];

    float* ws = (float*)d_ws;
    float* xl        = ws;                          // 3,200,000
    float* xr        = ws + 3200000;                // 3,200,000
    float* h1        = ws + 6400000;                // 3,200,000 (reused as h2)
    int*   sorted    = (int*)(ws + 9600000);        // 1,600,000
    int*   rowstart  = (int*)(ws + 11200000);       // 50,001
    int*   deg       = (int*)(ws + 11251000);       // 50,000  -- start of zero region
    int*   cursor    = (int*)(ws + 11301000);       // 50,000
    float* pooled    = ws + 11351000;               // 4,096
    float* cnt       = ws + 11355096;               // 64
    int*   blockSums = (int*)(ws + 11356000);       // 128
    int*   blockOff  = (int*)(ws + 11356128);       // 128

    // zero deg, cursor, pooled, cnt (contiguous)
    hipMemsetAsync(deg, 0, (size_t)(50000 + 50000 + 4096 + 64) * sizeof(float), stream);

    // ---- CSR build (dst-sorted edges) ----
    hist_kernel<<<(N_EDGES + 255) / 256, 256, 0, stream>>>(ei, deg);
    scan1_kernel<<<N_SCAN_BLOCKS, SCAN_BLK, 0, stream>>>(deg, rowstart, blockSums);
    scan2_kernel<<<1, 128, 0, stream>>>(blockSums, blockOff);
    scan3_kernel<<<(N_SCAN_BLOCKS * SCAN_BLK + 256) / 256, 256, 0, stream>>>(rowstart, blockOff);
    scatter_kernel<<<(N_EDGES + 255) / 256, 256, 0, stream>>>(ei, rowstart, cursor, sorted);

    // ---- layer 1 ----
    gemm_128_64<<<N_NODES, 128, 0, stream>>>(x, Wl1, Wr1, xl, xr);
    node_l1<<<N_NODES / 4, 256, 0, stream>>>(rowstart, sorted, xl, xr, att1, b1, h1);

    // ---- layer 2 (h2 reuses h1 buffer; gemm consumed h1 first) ----
    gemm_64_64<<<N_NODES, 128, 0, stream>>>(h1, Wl2, Wr2, xl, xr);
    node_l2<<<N_NODES / 4, 256, 0, stream>>>(rowstart, sorted, xl, xr, att2, b2, h1);

    // ---- pool + head ----
    pool_kernel<<<(N_NODES + 63) / 64, 64, 0, stream>>>(h1, batch, pooled, cnt);
    head_kernel<<<1, 128, 0, stream>>>(pooled, cnt, lin_w, lin_b, (float*)d_out);
}

// Round 4
// 452.841 us; speedup vs baseline: 2.5586x; 1.1802x over previous
//
#include <hip/hip_runtime.h>
#include <hip/hip_bf16.h>
#include <math.h>

#define N_NODES 50000
#define N_EDGES 1600000
#define N_GRAPHS 64
#define SCAN_BLK 512
#define N_SCAN_BLOCKS ((N_NODES + SCAN_BLK - 1) / SCAN_BLK)   // 98

// ---------------------------------------------------------------------------
// DPP cross-lane add helpers (VALU pipe, no LDS).
// ---------------------------------------------------------------------------
template <int CTRL>
__device__ __forceinline__ float dpp_add(float v) {
    int r = __builtin_amdgcn_update_dpp(0, __builtin_bit_cast(int, v), CTRL, 0xF, 0xF, true);
    return v + __builtin_bit_cast(float, r);
}

__device__ __forceinline__ float red16(float v) {
    v = dpp_add<0xB1>(v);    // quad_perm [1,0,3,2]
    v = dpp_add<0x4E>(v);    // quad_perm [2,3,0,1]
    v = dpp_add<0x141>(v);   // row_half_mirror
    v = dpp_add<0x140>(v);   // row_mirror
    return v;
}

__device__ __forceinline__ float edge_ev_l1(float xlv, float xrn, float attv) {
    float u = xlv + xrn;
    u = u > 0.f ? u : 0.2f * u;
    float v = red16(attv * u);
    v += __shfl_xor(v, 16);
    return __expf(v);
}

__device__ __forceinline__ float edge_ev_l2(float xlv, float xrn, float attv) {
    float u = xlv + xrn;
    u = u > 0.f ? u : 0.2f * u;
    float v = red16(attv * u);
    v += __shfl_xor(v, 16);
    v += __shfl_xor(v, 32);
    return __expf(v);
}

// ---------------------------------------------------------------------------
// Register-tiled dense transform: out = x @ [Wl | Wr], cols 0..63 -> xl,
// 64..127 -> xr. Block = 64 nodes, 256 threads = 4 waves.
// lane = node; wave w covers combined cols [w*32, w*32+32).
// W row slice is wave-uniform -> scalar (SMEM) loads feed FMAs as SGPRs.
// 32 independent accumulators/thread break the FMA dependency chain.
// ---------------------------------------------------------------------------
template <int K>
__global__ __launch_bounds__(256) void gemm_tiled(
    const float* __restrict__ x, const float* __restrict__ Wl,
    const float* __restrict__ Wr, float* __restrict__ xl, float* __restrict__ xr) {
    __shared__ float xs[64][K + 1];   // +1 pad: k-loop reads 2 lanes/bank (free)
    const int t = threadIdx.x;
    const int base = blockIdx.x * 64;
    // stage x tile (64 x K), coalesced float4 reads
    const int nf4 = 64 * K / 4;
    for (int f = t; f < nf4; f += 256) {
        const int row = f / (K / 4);
        const int c4 = f % (K / 4);
        float4 v = make_float4(0.f, 0.f, 0.f, 0.f);
        if (base + row < N_NODES)
            v = *(const float4*)(x + (size_t)(base + row) * K + c4 * 4);
        xs[row][c4 * 4 + 0] = v.x;
        xs[row][c4 * 4 + 1] = v.y;
        xs[row][c4 * 4 + 2] = v.z;
        xs[row][c4 * 4 + 3] = v.w;
    }
    __syncthreads();
    const int lane = t & 63;
    const int w = __builtin_amdgcn_readfirstlane(t >> 6);   // wave id (uniform)
    const float* __restrict__ W = (w < 2) ? Wl : Wr;
    const int cb = (w & 1) * 32;
    float acc[32];
#pragma unroll
    for (int j = 0; j < 32; ++j) acc[j] = 0.f;
#pragma unroll 2
    for (int k = 0; k < K; ++k) {
        const float xv = xs[lane][k];
        const float* __restrict__ Wrow = W + k * 64 + cb;   // wave-uniform
#pragma unroll
        for (int j = 0; j < 32; ++j) acc[j] = fmaf(xv, Wrow[j], acc[j]);
    }
    const int n = base + lane;
    if (n < N_NODES) {
        float* __restrict__ o = (w < 2) ? xl : xr;
#pragma unroll
        for (int j = 0; j < 32; j += 4) {
            float4 v = {acc[j], acc[j + 1], acc[j + 2], acc[j + 3]};
            *(float4*)(o + (size_t)n * 64 + cb + j) = v;
        }
    }
}

// ---------------------------------------------------------------------------
// CSR build: histogram by dst -> exclusive scan -> scatter src into dst order.
// ---------------------------------------------------------------------------
__global__ __launch_bounds__(256) void hist_kernel(
    const int* __restrict__ ei, int* __restrict__ deg) {
    const int e = blockIdx.x * 256 + threadIdx.x;
    if (e < N_EDGES) atomicAdd(&deg[ei[N_EDGES + e]], 1);
}

__global__ __launch_bounds__(SCAN_BLK) void scan1_kernel(
    const int* __restrict__ deg, int* __restrict__ rowstart,
    int* __restrict__ blockSums) {
    __shared__ int tmp[SCAN_BLK];
    const int t = threadIdx.x;
    const int idx = blockIdx.x * SCAN_BLK + t;
    const int v0 = (idx < N_NODES) ? deg[idx] : 0;
    tmp[t] = v0;
    __syncthreads();
    for (int off = 1; off < SCAN_BLK; off <<= 1) {
        int v = (t >= off) ? tmp[t - off] : 0;
        __syncthreads();
        tmp[t] += v;
        __syncthreads();
    }
    if (idx < N_NODES) rowstart[idx] = tmp[t] - v0;  // exclusive
    if (t == SCAN_BLK - 1) blockSums[blockIdx.x] = tmp[t];
}

__global__ __launch_bounds__(128) void scan2_kernel(
    const int* __restrict__ blockSums, int* __restrict__ blockOff) {
    __shared__ int tmp[128];
    const int t = threadIdx.x;
    const int v0 = (t < N_SCAN_BLOCKS) ? blockSums[t] : 0;
    tmp[t] = v0;
    __syncthreads();
    for (int off = 1; off < 128; off <<= 1) {
        int v = (t >= off) ? tmp[t - off] : 0;
        __syncthreads();
        tmp[t] += v;
        __syncthreads();
    }
    if (t < N_SCAN_BLOCKS) blockOff[t] = tmp[t] - v0;  // exclusive
}

__global__ __launch_bounds__(256) void scan3_kernel(
    int* __restrict__ rowstart, const int* __restrict__ blockOff) {
    const int idx = blockIdx.x * 256 + threadIdx.x;
    if (idx < N_NODES) rowstart[idx] += blockOff[idx / SCAN_BLK];
    else if (idx == N_NODES) rowstart[N_NODES] = N_EDGES;
}

__global__ __launch_bounds__(256) void scatter_kernel(
    const int* __restrict__ ei, const int* __restrict__ rowstart,
    int* __restrict__ cursor, int* __restrict__ sorted_src) {
    const int e = blockIdx.x * 256 + threadIdx.x;
    if (e >= N_EDGES) return;
    const int d = ei[N_EDGES + e];
    const int pos = atomicAdd(&cursor[d], 1);
    sorted_src[rowstart[d] + pos] = ei[e];
}

// ---------------------------------------------------------------------------
// Node-centric GATv2 layer: one wave per dst node, x4 unrolled ILP chains.
// ---------------------------------------------------------------------------
__global__ __launch_bounds__(256) void node_l1(
    const int* __restrict__ rowstart, const int* __restrict__ sorted_src,
    const float* __restrict__ xl, const float* __restrict__ xr,
    const float* __restrict__ att, const float* __restrict__ b1,
    float* __restrict__ h1) {
    const int n = (blockIdx.x * 256 + threadIdx.x) >> 6;
    const int lane = threadIdx.x & 63;
    const float xrn = xr[n * 64 + lane];
    const float xln = xl[n * 64 + lane];
    const float attv = att[lane];
    float ev = edge_ev_l1(xln, xrn, attv);   // self loop
    float accv = ev * xln;
    float ssum = ev;
    const int beg = __builtin_amdgcn_readfirstlane(rowstart[n]);
    const int end = __builtin_amdgcn_readfirstlane(rowstart[n + 1]);
    int i = beg;
    for (; i + 3 < end; i += 4) {
        const int s0 = sorted_src[i + 0];
        const int s1 = sorted_src[i + 1];
        const int s2 = sorted_src[i + 2];
        const int s3 = sorted_src[i + 3];
        const float a0 = xl[s0 * 64 + lane];
        const float a1 = xl[s1 * 64 + lane];
        const float a2 = xl[s2 * 64 + lane];
        const float a3 = xl[s3 * 64 + lane];
        const float e0 = edge_ev_l1(a0, xrn, attv);
        const float e1 = edge_ev_l1(a1, xrn, attv);
        const float e2 = edge_ev_l1(a2, xrn, attv);
        const float e3 = edge_ev_l1(a3, xrn, attv);
        accv = fmaf(e0, a0, accv);
        accv = fmaf(e1, a1, accv);
        accv = fmaf(e2, a2, accv);
        accv = fmaf(e3, a3, accv);
        ssum += (e0 + e1) + (e2 + e3);
    }
    for (; i < end; ++i) {
        const int src = sorted_src[i];
        const float xlv = xl[src * 64 + lane];
        const float e2 = edge_ev_l1(xlv, xrn, attv);
        accv = fmaf(e2, xlv, accv);
        ssum += e2;
    }
    float o = accv / (ssum + 1e-16f) + b1[lane];
    h1[n * 64 + lane] = o > 0.f ? o : expm1f(o);
}

__global__ __launch_bounds__(256) void node_l2(
    const int* __restrict__ rowstart, const int* __restrict__ sorted_src,
    const float* __restrict__ xl, const float* __restrict__ xr,
    const float* __restrict__ att, const float* __restrict__ b2,
    float* __restrict__ h2) {
    const int n = (blockIdx.x * 256 + threadIdx.x) >> 6;
    const int lane = threadIdx.x & 63;
    const float xrn = xr[n * 64 + lane];
    const float xln = xl[n * 64 + lane];
    const float attv = att[lane];
    float ev = edge_ev_l2(xln, xrn, attv);
    float accv = ev * xln;
    float ssum = ev;
    const int beg = __builtin_amdgcn_readfirstlane(rowstart[n]);
    const int end = __builtin_amdgcn_readfirstlane(rowstart[n + 1]);
    int i = beg;
    for (; i + 3 < end; i += 4) {
        const int s0 = sorted_src[i + 0];
        const int s1 = sorted_src[i + 1];
        const int s2 = sorted_src[i + 2];
        const int s3 = sorted_src[i + 3];
        const float a0 = xl[s0 * 64 + lane];
        const float a1 = xl[s1 * 64 + lane];
        const float a2 = xl[s2 * 64 + lane];
        const float a3 = xl[s3 * 64 + lane];
        const float e0 = edge_ev_l2(a0, xrn, attv);
        const float e1 = edge_ev_l2(a1, xrn, attv);
        const float e2 = edge_ev_l2(a2, xrn, attv);
        const float e3 = edge_ev_l2(a3, xrn, attv);
        accv = fmaf(e0, a0, accv);
        accv = fmaf(e1, a1, accv);
        accv = fmaf(e2, a2, accv);
        accv = fmaf(e3, a3, accv);
        ssum += (e0 + e1) + (e2 + e3);
    }
    for (; i < end; ++i) {
        const int src = sorted_src[i];
        const float xlv = xl[src * 64 + lane];
        const float e2 = edge_ev_l2(xlv, xrn, attv);
        accv = fmaf(e2, xlv, accv);
        ssum += e2;
    }
    float o = accv / (ssum + 1e-16f) + b2[lane];
    h2[n * 64 + lane] = o > 0.f ? o : expm1f(o);
}

// Mean-pool accumulation over sorted batch ids.
__global__ __launch_bounds__(64) void pool_kernel(
    const float* __restrict__ h2, const int* __restrict__ batch,
    float* __restrict__ pooled, float* __restrict__ cnt) {
    const int t = threadIdx.x;
    const int base = blockIdx.x * 64;
    float local = 0.f, lc = 0.f;
    int cur = -1;
    for (int j = 0; j < 64; ++j) {
        const int n = base + j;
        if (n >= N_NODES) break;
        const int g = batch[n];
        if (g != cur) {
            if (cur >= 0) {
                unsafeAtomicAdd(&pooled[cur * 64 + t], local);
                if (t == 0) unsafeAtomicAdd(&cnt[cur], lc);
            }
            cur = g; local = 0.f; lc = 0.f;
        }
        local += h2[n * 64 + t];
        lc += 1.f;
    }
    if (cur >= 0) {
        unsafeAtomicAdd(&pooled[cur * 64 + t], local);
        if (t == 0) unsafeAtomicAdd(&cnt[cur], lc);
    }
}

__global__ __launch_bounds__(128) void head_kernel(
    const float* __restrict__ pooled, const float* __restrict__ cnt,
    const float* __restrict__ lin_w, const float* __restrict__ lin_b,
    float* __restrict__ out) {
    const int i = threadIdx.x;          // 0..127 -> (g, k)
    const int g = i >> 1, k = i & 1;
    float c = cnt[g];
    c = c > 1.f ? c : 1.f;
    float a = 0.f;
#pragma unroll
    for (int j = 0; j < 64; ++j) a = fmaf(pooled[g * 64 + j] / c, lin_w[j * 2 + k], a);
    out[i] = a + lin_b[k];
}

extern "C" void kernel_launch(void* const* d_in, const int* in_sizes, int n_in,
                              void* d_out, int out_size, void* d_ws, size_t ws_size,
                              hipStream_t stream) {
    const float* x     = (const float*)d_in[0];
    const int*   ei    = (const int*)d_in[1];
    const int*   batch = (const int*)d_in[2];
    const float* Wl1   = (const float*)d_in[3];
    const float* Wr1   = (const float*)d_in[4];
    const float* att1  = (const float*)d_in[5];
    const float* b1    = (const float*)d_in[6];
    const float* Wl2   = (const float*)d_in[7];
    const float* Wr2   = (const float*)d_in[8];
    const float* att2  = (const float*)d_in[9];
    const float* b2    = (const float*)d_in[10];
    const float* lin_w = (const float*)d_in[11];
    const float* lin_b = (const float*)d_in[12];

    float* ws = (float*)d_ws;
    float* xl        = ws;                          // 3,200,000
    float* xr        = ws + 3200000;                // 3,200,000
    float* h1        = ws + 6400000;                // 3,200,000 (reused as h2)
    int*   sorted    = (int*)(ws + 9600000);        // 1,600,000
    int*   rowstart  = (int*)(ws + 11200000);       // 50,001
    int*   deg       = (int*)(ws + 11251000);       // 50,000  -- start of zero region
    int*   cursor    = (int*)(ws + 11301000);       // 50,000
    float* pooled    = ws + 11351000;               // 4,096
    float* cnt       = ws + 11355096;               // 64
    int*   blockSums = (int*)(ws + 11356000);       // 128
    int*   blockOff  = (int*)(ws + 11356128);       // 128

    // zero deg, cursor, pooled, cnt (contiguous)
    hipMemsetAsync(deg, 0, (size_t)(50000 + 50000 + 4096 + 64) * sizeof(float), stream);

    // ---- CSR build (dst-sorted edges) ----
    hist_kernel<<<(N_EDGES + 255) / 256, 256, 0, stream>>>(ei, deg);
    scan1_kernel<<<N_SCAN_BLOCKS, SCAN_BLK, 0, stream>>>(deg, rowstart, blockSums);
    scan2_kernel<<<1, 128, 0, stream>>>(blockSums, blockOff);
    scan3_kernel<<<(N_SCAN_BLOCKS * SCAN_BLK + 256) / 256, 256, 0, stream>>>(rowstart, blockOff);
    scatter_kernel<<<(N_EDGES + 255) / 256, 256, 0, stream>>>(ei, rowstart, cursor, sorted);

    const int gblocks = (N_NODES + 63) / 64;   // 782

    // ---- layer 1 ----
    gemm_tiled<128><<<gblocks, 256, 0, stream>>>(x, Wl1, Wr1, xl, xr);
    node_l1<<<N_NODES / 4, 256, 0, stream>>>(rowstart, sorted, xl, xr, att1, b1, h1);

    // ---- layer 2 (h2 reuses h1 buffer; gemm consumed h1 first) ----
    gemm_tiled<64><<<gblocks, 256, 0, stream>>>(h1, Wl2, Wr2, xl, xr);
    node_l2<<<N_NODES / 4, 256, 0, stream>>>(rowstart, sorted, xl, xr, att2, b2, h1);

    // ---- pool + head ----
    pool_kernel<<<(N_NODES + 63) / 64, 64, 0, stream>>>(h1, batch, pooled, cnt);
    head_kernel<<<1, 128, 0, stream>>>(pooled, cnt, lin_w, lin_b, (float*)d_out);
}